// Round 11
// baseline (684.911 us; speedup 1.0000x reference)
//
#include <hip/hip_runtime.h>

#define DEVI static __device__ __forceinline__

typedef short s16x8 __attribute__((ext_vector_type(8)));
typedef float f32x4 __attribute__((ext_vector_type(4)));
typedef unsigned short u16;

constexpr int BATCH = 32;
constexpr int NTOK  = 577;
constexpr int DIMC  = 768;
constexpr int NH    = 12;
constexpr int HD    = 64;
constexpr int NQKV  = 3 * DIMC;        // 2304
constexpr int MROWS = BATCH * NTOK;    // 18464
constexpr int NPAD  = 608;             // 19*32 padded token count
constexpr int NKT   = 38;              // 16-wide col tiles covering 608
constexpr int TSTR  = 2216;            // table slice stride (2210 padded to 16B mult)
constexpr float SCALE = 0.125f;        // 64^-0.5
constexpr float LOG2E = 1.44269504088896f;

// ---------- bf16 helpers (RNE) ----------
DEVI u16 f2b(float x) {
  unsigned u = __float_as_uint(x);
  u += 0x7fffu + ((u >> 16) & 1u);
  return (u16)(u >> 16);
}
DEVI float b2f(u16 h) { return __uint_as_float((unsigned)h << 16); }

DEVI void async16(void* lds, const void* g) {
  __builtin_amdgcn_global_load_lds((const __attribute__((address_space(1))) void*)g,
                                   (__attribute__((address_space(3))) void*)lds,
                                   16, 0, 0);
}
DEVI f32x4 mfma16(s16x8 a, s16x8 b, f32x4 c) {
  return __builtin_amdgcn_mfma_f32_16x16x32_bf16(a, b, c, 0, 0, 0);
}

// ---------- prep kernels ----------
__global__ __launch_bounds__(256) void split_plain(const float4* __restrict__ in,
                                                   ushort4* __restrict__ hi,
                                                   ushort4* __restrict__ lo, int n4) {
  int t = blockIdx.x * 256 + threadIdx.x;
  if (t >= n4) return;
  float4 v = in[t];
  ushort4 H, L;
  H.x = f2b(v.x); L.x = f2b(v.x - b2f(H.x));
  H.y = f2b(v.y); L.y = f2b(v.y - b2f(H.y));
  H.z = f2b(v.z); L.z = f2b(v.z - b2f(H.z));
  H.w = f2b(v.w); L.w = f2b(v.w - b2f(H.w));
  hi[t] = H; lo[t] = L;
}

__global__ __launch_bounds__(256) void split_transpose(const float* __restrict__ w,
                                                       u16* __restrict__ thi,
                                                       u16* __restrict__ tlo,
                                                       int K, int Nc) {
  int t = blockIdx.x * 256 + threadIdx.x;
  if (t >= K * Nc) return;
  int n = t / K, k = t - n * K;
  float v = w[(size_t)k * Nc + n];
  u16 h = f2b(v);
  thi[t] = h;
  tlo[t] = f2b(v - b2f(h));
}

// bias_table [2210][12] -> tabT [12][2216] bf16 (head-slice contiguous)
__global__ __launch_bounds__(256) void table_transpose(const float* __restrict__ tab,
                                                       u16* __restrict__ tabT) {
  int t = blockIdx.x * 256 + threadIdx.x;
  if (t >= NH * TSTR) return;
  int h = t / TSTR, i = t - h * TSTR;
  tabT[t] = (i < 2210) ? f2b(tab[(size_t)i * NH + h]) : (u16)0;
}

// ---------- fused 3-term split-bf16 GEMM, 2-phase double-buffered ----------
// L2 region blocking: 8 XCD regions = 4 mt-groups x 2 ntb-halves; bid&7 = XCD slot
// (hardware round-robin). Within a region: mt-major, ntb-fastest -> B half-panel
// (<=3.5MB) stays L2-resident; A panels stream once per ntb-half.
template <int MODE>
__global__ __launch_bounds__(256, 2) void gemm_split3(
    const u16* __restrict__ Ahi, const u16* __restrict__ Alo,
    const u16* __restrict__ Bhi, const u16* __restrict__ Blo,
    int M, int Nn, int K, int ntn, int MT,
    float* __restrict__ outF, const float* __restrict__ pbias,
    u16* __restrict__ qb, u16* __restrict__ kb, u16* __restrict__ vt) {
  __shared__ __align__(16) u16 Ah[2][128 * 32];
  __shared__ __align__(16) u16 Al[2][128 * 32];
  __shared__ __align__(16) u16 Bh[2][128 * 32];
  __shared__ __align__(16) u16 Bl[2][128 * 32];
  const int tid = threadIdx.x;
  const int lane = tid & 63, wv = tid >> 6;
  const int g = lane >> 4, c = lane & 15;

  // region mapping
  const int bid = blockIdx.x;
  const int x = bid & 7;                 // XCD slot
  const int gy = x >> 1, gx = x & 1;     // mt-group, ntb-half
  const int base = MT >> 2, rem = MT & 3;
  const int gsz = base + (gy < rem);
  const int mt_start = gy * base + (gy < rem ? gy : rem);
  const int nh = ntn >> 1;
  const int i = bid >> 3;
  if (i >= gsz * nh) return;
  const int mt = mt_start + i / nh;
  const int ntb = gx * nh + i % nh;
  const int m0 = mt * 128, n0 = ntb * 128;
  const int wr = wv >> 1, wc = wv & 1;

  f32x4 acc[4][4] = {};

  const int ch0 = tid, ch1 = 256 + tid;
  const int r0 = ch0 >> 2, gk0 = (((ch0 & 3) ^ ((r0 >> 1) & 3)) * 8);
  const int r1 = ch1 >> 2, gk1 = (((ch1 & 3) ^ ((r1 >> 1) & 3)) * 8);
  const int ar0 = (m0 + r0 < M) ? (m0 + r0) : (M - 1);
  const int ar1 = (m0 + r1 < M) ? (m0 + r1) : (M - 1);
  const int br0 = n0 + r0, br1 = n0 + r1;

  const u16* ah0 = Ahi + (size_t)ar0 * K + gk0;
  const u16* ah1 = Ahi + (size_t)ar1 * K + gk1;
  const u16* al0 = Alo + (size_t)ar0 * K + gk0;
  const u16* al1 = Alo + (size_t)ar1 * K + gk1;
  const u16* bh0 = Bhi + (size_t)br0 * K + gk0;
  const u16* bh1 = Bhi + (size_t)br1 * K + gk1;
  const u16* bl0 = Blo + (size_t)br0 * K + gk0;
  const u16* bl1 = Blo + (size_t)br1 * K + gk1;

  auto STAGE = [&](int buf, int kk) {
    async16(&Ah[buf][ch0 * 8], ah0 + kk);
    async16(&Ah[buf][ch1 * 8], ah1 + kk);
    async16(&Al[buf][ch0 * 8], al0 + kk);
    async16(&Al[buf][ch1 * 8], al1 + kk);
    async16(&Bh[buf][ch0 * 8], bh0 + kk);
    async16(&Bh[buf][ch1 * 8], bh1 + kk);
    async16(&Bl[buf][ch0 * 8], bl0 + kk);
    async16(&Bl[buf][ch1 * 8], bl1 + kk);
  };
  auto COMPUTE = [&](int buf) {
    s16x8 afh[4], afl[4];
#pragma unroll
    for (int mi = 0; mi < 4; ++mi) {
      int row = wr * 64 + mi * 16 + c;
      int sl = g ^ ((row >> 1) & 3);
      afh[mi] = *(const s16x8*)&Ah[buf][row * 32 + sl * 8];
      afl[mi] = *(const s16x8*)&Al[buf][row * 32 + sl * 8];
    }
#pragma unroll
    for (int ni = 0; ni < 4; ++ni) {
      int row = wc * 64 + ni * 16 + c;
      int sl = g ^ ((row >> 1) & 3);
      s16x8 bfh = *(const s16x8*)&Bh[buf][row * 32 + sl * 8];
      s16x8 bfl = *(const s16x8*)&Bl[buf][row * 32 + sl * 8];
#pragma unroll
      for (int mi = 0; mi < 4; ++mi) {
        f32x4 t0 = mfma16(afh[mi], bfl, acc[mi][ni]);
        t0 = mfma16(afl[mi], bfh, t0);
        acc[mi][ni] = mfma16(afh[mi], bfh, t0);
      }
    }
  };

  STAGE(0, 0);
  __syncthreads();
  for (int kk = 0; kk < K; kk += 64) {
    if (kk + 32 < K) STAGE(1, kk + 32);
    COMPUTE(0);
    __syncthreads();
    if (kk + 64 < K) STAGE(0, kk + 64);
    COMPUTE(1);
    __syncthreads();
  }

#pragma unroll
  for (int mi = 0; mi < 4; ++mi) {
#pragma unroll
    for (int ni = 0; ni < 4; ++ni) {
#pragma unroll
      for (int r = 0; r < 4; ++r) {
        int row = m0 + wr * 64 + mi * 16 + g * 4 + r;
        int col = n0 + wc * 64 + ni * 16 + c;
        if (row < M) {
          float v = acc[mi][ni][r];
          if constexpr (MODE == 0) {
            outF[(size_t)row * Nn + col] = v + pbias[col];
          } else {
            int b = row / NTOK, tok = row - b * NTOK;
            int s = col / DIMC, rrx = col - s * DIMC;
            int h = rrx >> 6, d = rrx & 63;
            size_t bh = (size_t)b * NH + h;
            if (s == 2) {
              vt[(bh * HD + d) * NPAD + tok] = f2b(v);  // V transposed
            } else {
              u16* dst = (s == 0) ? qb : kb;
              dst[(bh * NPAD + tok) * HD + d] = f2b(v);
            }
          }
        }
      }
    }
  }
}

// ---------- attention ----------
// Bias computed in-kernel from 4.4KB head-slice table in LDS (aliased into SLAB).
// XCD swizzle co-locates the 19 q-tiles of each (b,h) -> K/V L2-resident.
// O written via LDS stage for full-cacheline coalesced stores.
__global__ __launch_bounds__(256) void attn_kernel(
    const u16* __restrict__ qb, const u16* __restrict__ kb, const u16* __restrict__ vt,
    const u16* __restrict__ tabT, u16* __restrict__ aohi, u16* __restrict__ aolo) {
  __shared__ __align__(16) u16 SLAB[32 * NPAD];   // 38912 B; aliases: bias table, P, O-stage
  __shared__ float redm[4][32];
  __shared__ float reds[4][32];
  const int tid = threadIdx.x, lane = tid & 63, wv = tid >> 6;
  const int g = lane >> 4, c = lane & 15;

  // XCD co-location: 7296 = 8 * 912
  const int work = (blockIdx.x & 7) * 912 + (blockIdx.x >> 3);
  const int qt = work % 19;
  const int bh = work / 19;
  const int h = bh % NH;
  const int b = bh / NH;
  const int q0 = qt * 32;

  // --- stage bias table slice (2216 u16 = 277 x 16B) into SLAB[0..2216) ---
  {
    const char* tsrc = (const char*)(tabT + (size_t)h * TSTR);
    for (int t = tid; t < 277; t += 256) async16(&SLAB[t * 8], tsrc + (size_t)t * 16);
  }

  // --- Q fragments ---
  s16x8 qf[2][2];
#pragma unroll
  for (int mf = 0; mf < 2; ++mf)
#pragma unroll
    for (int ks = 0; ks < 2; ++ks)
      qf[mf][ks] = *(const s16x8*)(qb + ((size_t)bh * NPAD + q0 + mf * 16 + c) * HD + ks * 32 + g * 8);

  // --- QK^T: wave wv owns tiles t = wv + 4j ---
  f32x4 sacc[10][2];
#pragma unroll
  for (int j = 0; j < 10; ++j) {
    int t = wv + 4 * j;
    f32x4 z = {0.f, 0.f, 0.f, 0.f};
    sacc[j][0] = z; sacc[j][1] = z;
    if (t < NKT) {
#pragma unroll
      for (int ks = 0; ks < 2; ++ks) {
        s16x8 kf = *(const s16x8*)(kb + ((size_t)bh * NPAD + t * 16 + c) * HD + ks * 32 + g * 8);
        sacc[j][0] = mfma16(qf[0][ks], kf, sacc[j][0]);
        sacc[j][1] = mfma16(qf[1][ks], kf, sacc[j][1]);
      }
    }
  }

  __syncthreads();  // table resident (barrier drains global_load_lds)

  // --- q-row geometry (8 rows per thread) ---
  int qrow[2][4], qh_[2][4], qw_[2][4];
#pragma unroll
  for (int mf = 0; mf < 2; ++mf)
#pragma unroll
    for (int r = 0; r < 4; ++r) {
      int q = q0 + mf * 16 + g * 4 + r;
      qrow[mf][r] = q;
      int qi = q - 1; if (qi < 0) qi = 0; if (qi > 575) qi = 575;
      qh_[mf][r] = qi / 24;
      qw_[mf][r] = qi - qh_[mf][r] * 24;
    }

  // --- scale + bias (LDS table gather) + mask; row max ---
  float rmax[2][4];
#pragma unroll
  for (int mf = 0; mf < 2; ++mf)
#pragma unroll
    for (int r = 0; r < 4; ++r) rmax[mf][r] = -1e30f;
#pragma unroll
  for (int j = 0; j < 10; ++j) {
    int t = wv + 4 * j;
    if (t < NKT) {
      int kcol = t * 16 + c;
      int ki = kcol - 1; if (ki < 0) ki = 0; if (ki > 575) ki = 575;
      int kh = ki / 24, kw = ki - kh * 24;
#pragma unroll
      for (int mf = 0; mf < 2; ++mf) {
#pragma unroll
        for (int r = 0; r < 4; ++r) {
          int idx = (qh_[mf][r] - kh + 23) * 47 + (qw_[mf][r] - kw + 23);
          if (qrow[mf][r] == 0 || kcol == 0) idx = 0;
          float bias = b2f(SLAB[idx]);
          float sv;
          if (qrow[mf][r] < NTOK && kcol < NTOK)
            sv = sacc[j][mf][r] * SCALE + bias;
          else
            sv = -1e30f;
          sacc[j][mf][r] = sv;
          rmax[mf][r] = fmaxf(rmax[mf][r], sv);
        }
      }
    }
  }
#pragma unroll
  for (int d = 1; d < 16; d <<= 1)
#pragma unroll
    for (int mf = 0; mf < 2; ++mf)
#pragma unroll
      for (int r = 0; r < 4; ++r)
        rmax[mf][r] = fmaxf(rmax[mf][r], __shfl_xor(rmax[mf][r], d));
  if (c == 0) {
#pragma unroll
    for (int mf = 0; mf < 2; ++mf)
#pragma unroll
      for (int r = 0; r < 4; ++r) redm[wv][mf * 16 + g * 4 + r] = rmax[mf][r];
  }
  __syncthreads();  // all bias reads done; safe to overwrite SLAB with P
  float fmx[2][4];
#pragma unroll
  for (int mf = 0; mf < 2; ++mf)
#pragma unroll
    for (int r = 0; r < 4; ++r) {
      int row = mf * 16 + g * 4 + r;
      fmx[mf][r] = fmaxf(fmaxf(redm[0][row], redm[1][row]), fmaxf(redm[2][row], redm[3][row]));
    }

  // --- exp -> P into SLAB (swizzled), row sums ---
  float rsum[2][4] = {};
#pragma unroll
  for (int j = 0; j < 10; ++j) {
    int t = wv + 4 * j;
    if (t < NKT) {
      int kcol = t * 16 + c;
#pragma unroll
      for (int mf = 0; mf < 2; ++mf)
#pragma unroll
        for (int r = 0; r < 4; ++r) {
          int lrow = mf * 16 + g * 4 + r;
          float p = exp2f((sacc[j][mf][r] - fmx[mf][r]) * LOG2E);
          rsum[mf][r] += p;
          SLAB[lrow * NPAD + (kcol ^ ((lrow & 3) << 3))] = f2b(p);
        }
    }
  }
#pragma unroll
  for (int d = 1; d < 16; d <<= 1)
#pragma unroll
    for (int mf = 0; mf < 2; ++mf)
#pragma unroll
      for (int r = 0; r < 4; ++r) rsum[mf][r] += __shfl_xor(rsum[mf][r], d);
  if (c == 0) {
#pragma unroll
    for (int mf = 0; mf < 2; ++mf)
#pragma unroll
      for (int r = 0; r < 4; ++r) reds[wv][mf * 16 + g * 4 + r] = rsum[mf][r];
  }
  __syncthreads();  // P written + sums available
  float fsm[2][4];
#pragma unroll
  for (int mf = 0; mf < 2; ++mf)
#pragma unroll
    for (int r = 0; r < 4; ++r) {
      int row = mf * 16 + g * 4 + r;
      fsm[mf][r] = (reds[0][row] + reds[1][row]) + (reds[2][row] + reds[3][row]);
    }

  // --- PV: wave wv owns d-cols [wv*16, wv*16+16) ---
  f32x4 oacc[2] = {};
  for (int ks = 0; ks < 19; ++ks) {
    int col = ks * 32 + g * 8;
    s16x8 pf0 = *(const s16x8*)&SLAB[c * NPAD + (col ^ ((c & 3) << 3))];
    s16x8 pf1 = *(const s16x8*)&SLAB[(16 + c) * NPAD + (col ^ ((c & 3) << 3))];
    s16x8 vf = *(const s16x8*)(vt + ((size_t)bh * HD + wv * 16 + c) * NPAD + col);
    oacc[0] = mfma16(pf0, vf, oacc[0]);
    oacc[1] = mfma16(pf1, vf, oacc[1]);
  }

  __syncthreads();  // all P reads done; reuse SLAB for O staging

  // --- normalize + hi/lo into LDS (stride 68 spreads g across banks) ---
#pragma unroll
  for (int mf = 0; mf < 2; ++mf) {
#pragma unroll
    for (int r = 0; r < 4; ++r) {
      int tokl = mf * 16 + g * 4 + r;
      int d = wv * 16 + c;
      float v = oacc[mf][r] / fsm[mf][r];
      u16 hi = f2b(v);
      SLAB[tokl * 68 + d] = hi;
      SLAB[2176 + tokl * 68 + d] = f2b(v - b2f(hi));
    }
  }
  __syncthreads();

  // --- coalesced copy-out: 32 rows x 128B per array, full cachelines ---
  {
    int row = tid >> 3, seg = tid & 7;
    int tok = q0 + row;
    if (tok < NTOK) {
      size_t base = ((size_t)b * NTOK + tok) * DIMC + h * HD + seg * 8;
      u16 vh[8], vl[8];
#pragma unroll
      for (int e = 0; e < 8; ++e) {
        vh[e] = SLAB[row * 68 + seg * 8 + e];
        vl[e] = SLAB[2176 + row * 68 + seg * 8 + e];
      }
      *(s16x8*)(aohi + base) = *(s16x8*)vh;
      *(s16x8*)(aolo + base) = *(s16x8*)vl;
    }
  }
}

// ---------- launch ----------
extern "C" void kernel_launch(void* const* d_in, const int* in_sizes, int n_in,
                              void* d_out, int out_size, void* d_ws, size_t ws_size,
                              hipStream_t stream) {
  const float* x      = (const float*)d_in[0];
  const float* qkv_w  = (const float*)d_in[1];
  const float* btab   = (const float*)d_in[2];
  const float* proj_w = (const float*)d_in[3];
  const float* proj_b = (const float*)d_in[4];
  const int*   rel    = (const int*)d_in[5];
  (void)rel;
  float* out = (float*)d_out;

  char* ws = (char*)d_ws;
  size_t off = 0;
  auto alloc = [&](size_t bytes) {
    void* p = ws + off;
    off += (bytes + 255) & ~(size_t)255;
    return p;
  };
  constexpr size_t SZ_QKVB = (size_t)BATCH * NH * NPAD * HD * 2;
  u16* qb = (u16*)alloc(SZ_QKVB);
  u16* kb = (u16*)alloc(SZ_QKVB);
  u16* vt = (u16*)alloc(SZ_QKVB);
  u16* tabT = (u16*)alloc((size_t)NH * TSTR * 2);   // 53 KB head-major bias table
  u16* wth = (u16*)alloc((size_t)NQKV * DIMC * 2);
  u16* wtl = (u16*)alloc((size_t)NQKV * DIMC * 2);
  u16* w2h = (u16*)alloc((size_t)DIMC * DIMC * 2);
  u16* w2l = (u16*)alloc((size_t)DIMC * DIMC * 2);
  u16* xhi = (u16*)alloc((size_t)MROWS * DIMC * 2);
  u16* xlo = (u16*)alloc((size_t)MROWS * DIMC * 2);
  u16* aohi = xhi;  // x-split dead after QKV GEMM -> reuse
  u16* aolo = xlo;

  dim3 blk(256);
  {
    int n4 = MROWS * DIMC / 4;
    split_plain<<<(n4 + 255) / 256, blk, 0, stream>>>((const float4*)x, (ushort4*)xhi, (ushort4*)xlo, n4);
  }
  {
    int n = DIMC * NQKV;
    split_transpose<<<(n + 255) / 256, blk, 0, stream>>>(qkv_w, wth, wtl, DIMC, NQKV);
  }
  {
    int n = DIMC * DIMC;
    split_transpose<<<(n + 255) / 256, blk, 0, stream>>>(proj_w, w2h, w2l, DIMC, DIMC);
  }
  {
    int n = NH * TSTR;
    table_transpose<<<(n + 255) / 256, blk, 0, stream>>>(btab, tabT);
  }
  {
    // QKV GEMM: MT=145 m-tiles, 18 n-tiles; grid = 8 regions x maxregion(37*9)
    int MT = (MROWS + 127) / 128;  // 145
    int nt = NQKV / 128;           // 18
    int grid = 8 * ((MT >> 2) + 1) * (nt >> 1);   // 8*37*9 = 2664
    gemm_split3<1><<<grid, blk, 0, stream>>>(xhi, xlo, wth, wtl, MROWS, NQKV, DIMC, nt, MT,
                                             nullptr, nullptr, qb, kb, vt);
  }
  attn_kernel<<<BATCH * NH * 19, blk, 0, stream>>>(qb, kb, vt, tabT, aohi, aolo);
  {
    // proj GEMM: MT=145, 6 n-tiles; grid = 8 * 37 * 3 = 888
    int MT = (MROWS + 127) / 128;  // 145
    int nt = DIMC / 128;           // 6
    int grid = 8 * ((MT >> 2) + 1) * (nt >> 1);
    gemm_split3<0><<<grid, blk, 0, stream>>>(aohi, aolo, w2h, w2l, MROWS, DIMC, DIMC, nt, MT,
                                             out, proj_b, nullptr, nullptr, nullptr);
  }
}